// Round 7
// baseline (4251.990 us; speedup 1.0000x reference)
//
#include <hip/hip_runtime.h>

// GATRNN: T=12 steps of {GAT1(inputs_t) -> GRU -> GAT2}, then Linear(H->D).
// fp32 I/O. Graph hardcoded: edge k: sender=k/63, receiver=k%63; node 63 inert.
// R7 = R6 with the LDS OOB fixed (sef/spr were written past the end of sscr,
// clobbering sW2t/soW). Phase A (GRU GEMM) is an LDS-tiled GEMM: Whh staged
// per 32-k slice, register tile 8n x 6c ({c,c+1} x 3 gates -> gating local).

#define T_   12
#define B_   32
#define N_   64
#define D_   2
#define H_   128
#define HID_ 32
#define HEAD_ 4
#define NA_  63
#define SHP  132   // sh row stride
#define SWP  36    // staged-weight row stride

__device__ __forceinline__ float eluf(float x){ return x>0.f ? x : expm1f(x); }

// ---- ws layout (floats) ----
#define OFF_X1  0u           // T*B*N*HID  = 786432
#define OFF_PS1 786432u      // T*B*N*HEAD =  98304
#define OFF_PR1 884736u      //            =  98304
#define OFF_XG  983040u      // T*B*N*H    = 3145728
#define OFF_GI  4128768u     // T*B*384*64 = 9437184   layout [t][b][c][n]

// ---------------- GAT1 fc1 + edge projections, grid T*B x 256 ----------------
__global__ __launch_bounds__(256, 4) void gat1_fc(
    const float* __restrict__ inp, const float* __restrict__ W1,
    const float* __restrict__ b1, const float* __restrict__ W2,
    const float* __restrict__ b2,
    float* __restrict__ x1_all, float* __restrict__ ps_all,
    float* __restrict__ pr_all){
  int grp = blockIdx.x;
  int tid = threadIdx.x;
  __shared__ float sx1[N_*HID_];
  __shared__ float sW1[HID_*D_];
  __shared__ float sb1[HID_];
  __shared__ float sW2[HEAD_*2*HID_];
  __shared__ float sxin[N_*D_];
  if(tid < 64)  sW1[tid] = W1[tid];
  if(tid < 32)  sb1[tid] = b1[tid];
  sW2[tid] = W2[tid];
  if(tid < 128) sxin[tid] = inp[grp*N_*D_ + tid];
  __syncthreads();
  for(int o = tid; o < N_*HID_; o += 256){
    int n = o >> 5, k = o & 31;
    float v = sb1[k] + sxin[n*2]*sW1[k*2] + sxin[n*2+1]*sW1[k*2+1];
    sx1[o] = v;
    x1_all[grp*N_*HID_ + o] = v;
  }
  __syncthreads();
  for(int p = tid; p < N_*8; p += 256){
    int n = p >> 3, q = p & 7, hh = q & 3;
    const float* w  = sW2 + hh*64 + ((q < 4) ? 0 : 32);
    const float* xr = sx1 + n*32;
    float acc = (q < 4) ? b2[hh] : 0.f;
    #pragma unroll
    for(int c = 0; c < 32; c++) acc += xr[c]*w[c];
    if(q < 4) ps_all[grp*N_*HEAD_ + n*4 + hh] = acc;
    else      pr_all[grp*N_*HEAD_ + n*4 + hh] = acc;
  }
}

// ---- GAT1 attention: one block per (t,b), 64 receivers. grid T*B x 512 ----
__global__ __launch_bounds__(512, 2) void att64(const float* __restrict__ x1,
                                                const float* __restrict__ ps,
                                                const float* __restrict__ pr,
                                                float* __restrict__ out){
  __shared__ float sxp[NA_*33];
  __shared__ float sps[256];
  __shared__ float sscr[16*256];
  int grp = blockIdx.x, tid = threadIdx.x;
  const float* x1g = x1 + (size_t)grp * (N_*HID_);
  const float* psg = ps + (size_t)grp * (N_*HEAD_);
  for(int slot = tid; slot < NA_*HID_; slot += 512){
    int i = slot >> 5, d = slot & 31;
    sxp[i*33 + d] = x1g[slot];
  }
  if(tid < NA_*HEAD_) sps[tid] = psg[tid];
  __syncthreads();
  int sg = tid >> 5, l = tid & 31;
  float* scr = sscr + sg*256;
  #pragma unroll
  for(int rep = 0; rep < 4; rep++){
    int j = sg*4 + rep;
    int idx = grp*64 + j;
    float* orow = out + (size_t)idx * H_;
    if(j == NA_){
      #pragma unroll
      for(int q = 0; q < 4; q++) orow[q*32 + l] = 0.f;
    } else {
      float prj = pr[(size_t)idx*4 + (l & 3)];
      int hh = l & 3, i0 = l >> 2;
      float pmax = -1e30f;
      #pragma unroll
      for(int k = 0; k < 8; k++){
        int i = i0 + 8*k;
        if(i < NA_){
          float v = eluf(sps[i*4 + hh] + prj);
          scr[i*4 + hh] = v;
          pmax = fmaxf(pmax, v);
        }
      }
      #pragma unroll
      for(int st = 4; st < 32; st <<= 1) pmax = fmaxf(pmax, __shfl_xor(pmax, st, 32));
      float psum = 0.f;
      #pragma unroll
      for(int k = 0; k < 8; k++){
        int i = i0 + 8*k;
        if(i < NA_){
          float e = expf(scr[i*4 + hh] - pmax);
          scr[i*4 + hh] = e;
          psum += e;
        }
      }
      #pragma unroll
      for(int st = 4; st < 32; st <<= 1) psum += __shfl_xor(psum, st, 32);
      if(i0 == 0) scr[252 + hh] = psum;
      float a0=0.f, a1=0.f, a2=0.f, a3=0.f;
      for(int i = 0; i < NA_; i++){
        float4 e4 = *(const float4*)&scr[i*4];
        float xv = sxp[i*33 + l];
        a0 += e4.x*xv; a1 += e4.y*xv; a2 += e4.z*xv; a3 += e4.w*xv;
      }
      orow[     l] = eluf(a0 / scr[252]);
      orow[32 + l] = eluf(a1 / scr[253]);
      orow[64 + l] = eluf(a2 / scr[254]);
      orow[96 + l] = eluf(a3 / scr[255]);
    }
  }
}

// ---- gi[t][b][c][n] = (xg@Wih^T)[n][c] + bih[c] + (c<256 ? bhh[c] : 0) ----
__global__ __launch_bounds__(512, 2) void gi_k(const float* __restrict__ xg,
                                               const float* __restrict__ Wih,
                                               const float* __restrict__ bih,
                                               const float* __restrict__ bhh,
                                               float* __restrict__ gi){
  __shared__ float sxg[64*SHP];
  __shared__ float sWb[384*SWP];
  int tb = blockIdx.x, tid = threadIdx.x;
  const float* xr = xg + (size_t)tb*(N_*H_);
  for(int slot = tid; slot < 2048; slot += 512){
    int n = slot >> 5, q = slot & 31;
    *(float4*)&sxg[n*SHP + q*4] = *(const float4*)&xr[n*H_ + q*4];
  }
  int nt = tid & 7, ct = tid >> 3;
  int c128 = ct*2;
  int cr[6] = {c128, c128+1, 128+c128, 128+c128+1, 256+c128, 256+c128+1};
  float acc[8][6];
  #pragma unroll
  for(int j = 0; j < 6; j++){
    int c = cr[j];
    float bias = bih[c] + ((c < 256) ? bhh[c] : 0.f);
    #pragma unroll
    for(int i = 0; i < 8; i++) acc[i][j] = bias;
  }
  for(int s = 0; s < 4; s++){
    __syncthreads();
    #pragma unroll
    for(int rep = 0; rep < 6; rep++){
      int slot = tid + 512*rep;
      int c = slot >> 3, q = slot & 7;
      *(float4*)&sWb[c*SWP + q*4] = *(const float4*)&Wih[(size_t)c*H_ + s*32 + q*4];
    }
    __syncthreads();
    #pragma unroll
    for(int kb = 0; kb < 8; kb++){
      float4 w[6], hv[8];
      #pragma unroll
      for(int j = 0; j < 6; j++) w[j] = *(const float4*)&sWb[cr[j]*SWP + kb*4];
      #pragma unroll
      for(int i = 0; i < 8; i++) hv[i] = *(const float4*)&sxg[(nt+8*i)*SHP + s*32 + kb*4];
      #pragma unroll
      for(int i = 0; i < 8; i++){
        #pragma unroll
        for(int j = 0; j < 6; j++){
          acc[i][j] += w[j].x*hv[i].x + w[j].y*hv[i].y + w[j].z*hv[i].z + w[j].w*hv[i].w;
        }
      }
    }
  }
  float* go = gi + (size_t)tb*384*64;
  #pragma unroll
  for(int j = 0; j < 6; j++){
    #pragma unroll
    for(int i = 0; i < 8; i++) go[(size_t)cr[j]*64 + nt + 8*i] = acc[i][j];
  }
}

// ---------------- persistent per-batch T-loop. grid 32 x 512 ----------------
__global__ __launch_bounds__(512, 2) void loop_k(
    const float* __restrict__ gi_all, const float* __restrict__ h0,
    const float* __restrict__ Whh, const float* __restrict__ bhh,
    const float* __restrict__ W1, const float* __restrict__ b1,
    const float* __restrict__ W2, const float* __restrict__ b2,
    const float* __restrict__ oW, const float* __restrict__ ob,
    float* __restrict__ pred){
  __shared__ float sh[64*SHP];     // 33.8 KB, persists across steps
  __shared__ float sWb[384*SWP];   // 55.3 KB staged Whh k-slice
  __shared__ float sW1[32*H_];     // 16 KB
  __shared__ float sx2[64*33];     // 8.4 KB
  __shared__ float sscr[16*256];   // 16 KB (per-subgroup attention scratch)
  __shared__ float sef[256];       // sender projections (+b2)
  __shared__ float spr[256];       // receiver projections
  __shared__ float sW2t[8*33];
  __shared__ float sb1[32], sob[2], soW[2*H_];
  int tid = threadIdx.x, b = blockIdx.x;

  for(int i = tid; i < N_*H_; i += 512){
    int r = i >> 7, k = i & 127;
    sh[r*SHP + k] = h0[(size_t)b*N_*H_ + i];
  }
  for(int i = tid; i < 32*H_; i += 512) sW1[i] = W1[i];
  if(tid < 256){
    int q = tid >> 5, cc = tid & 31;
    sW2t[q*33 + cc] = W2[(q&3)*64 + ((q < 4) ? 0 : 32) + cc];
  }
  if(tid < 32) sb1[tid] = b1[tid];
  if(tid < 256) soW[tid] = oW[tid];
  if(tid < 2) sob[tid] = ob[tid];

  int nt = tid & 7, ct = tid >> 3;      // phase-A tile coords
  int c128 = ct*2;
  int cr[6] = {c128, c128+1, 128+c128, 128+c128+1, 256+c128, 256+c128+1};
  float bhn0 = bhh[256 + c128], bhn1 = bhh[256 + c128 + 1];
  int sg = tid >> 5, l = tid & 31;      // phase-C coords
  int g = tid >> 6;                     // phase-B1 coords (wave-uniform)
  __syncthreads();

  for(int t = 0; t < T_; t++){
    // ================= phase A: GRU (LDS-tiled GEMM) =================
    const float* gip = gi_all + ((size_t)t*B_ + b)*384*64;
    float acc[8][6], gn0[8], gn1[8];
    #pragma unroll
    for(int i = 0; i < 8; i++){
      int n = nt + 8*i;
      acc[i][0] = gip[(size_t)(c128    )*64 + n];
      acc[i][1] = gip[(size_t)(c128+1  )*64 + n];
      acc[i][2] = gip[(size_t)(c128+128)*64 + n];
      acc[i][3] = gip[(size_t)(c128+129)*64 + n];
      acc[i][4] = 0.f;
      acc[i][5] = 0.f;
      gn0[i] = gip[(size_t)(c128+256)*64 + n];
      gn1[i] = gip[(size_t)(c128+257)*64 + n];
    }
    for(int s = 0; s < 4; s++){
      __syncthreads();
      #pragma unroll
      for(int rep = 0; rep < 6; rep++){
        int slot = tid + 512*rep;
        int c = slot >> 3, q = slot & 7;
        *(float4*)&sWb[c*SWP + q*4] = *(const float4*)&Whh[(size_t)c*H_ + s*32 + q*4];
      }
      __syncthreads();
      #pragma unroll
      for(int kb = 0; kb < 8; kb++){
        float4 w[6], hv[8];
        #pragma unroll
        for(int j = 0; j < 6; j++) w[j] = *(const float4*)&sWb[cr[j]*SWP + kb*4];
        #pragma unroll
        for(int i = 0; i < 8; i++) hv[i] = *(const float4*)&sh[(nt+8*i)*SHP + s*32 + kb*4];
        #pragma unroll
        for(int i = 0; i < 8; i++){
          #pragma unroll
          for(int j = 0; j < 6; j++){
            acc[i][j] += w[j].x*hv[i].x + w[j].y*hv[i].y + w[j].z*hv[i].z + w[j].w*hv[i].w;
          }
        }
      }
    }
    float hnew[8][2];
    #pragma unroll
    for(int i = 0; i < 8; i++){
      int n = nt + 8*i;
      float hp0 = sh[n*SHP + c128], hp1 = sh[n*SHP + c128 + 1];
      float r0 = 1.f/(1.f + expf(-acc[i][0]));
      float r1 = 1.f/(1.f + expf(-acc[i][1]));
      float z0 = 1.f/(1.f + expf(-acc[i][2]));
      float z1 = 1.f/(1.f + expf(-acc[i][3]));
      float ng0 = tanhf(gn0[i] + r0*(acc[i][4] + bhn0));
      float ng1 = tanhf(gn1[i] + r1*(acc[i][5] + bhn1));
      hnew[i][0] = (1.f - z0)*ng0 + z0*hp0;
      hnew[i][1] = (1.f - z1)*ng1 + z1*hp1;
    }
    __syncthreads();
    #pragma unroll
    for(int i = 0; i < 8; i++){
      int n = nt + 8*i;
      sh[n*SHP + c128]     = hnew[i][0];
      sh[n*SHP + c128 + 1] = hnew[i][1];
    }
    __syncthreads();

    // ================= phase B1: x2 = h@W1^T + b1 =================
    {
      int n = tid & 63;
      float a[4] = {sb1[g*4], sb1[g*4+1], sb1[g*4+2], sb1[g*4+3]};
      #pragma unroll 4
      for(int k4 = 0; k4 < 32; k4++){
        float4 hv = *(const float4*)&sh[n*SHP + k4*4];
        #pragma unroll
        for(int q = 0; q < 4; q++){
          float4 w = *(const float4*)&sW1[(g*4+q)*H_ + k4*4];
          a[q] += w.x*hv.x + w.y*hv.y + w.z*hv.z + w.w*hv.w;
        }
      }
      #pragma unroll
      for(int q = 0; q < 4; q++) sx2[n*33 + g*4 + q] = a[q];
    }
    __syncthreads();
    // ================= phase B2: edge projections =================
    {
      int rr = tid >> 3, q = tid & 7, hh = q & 3;
      float a = (q < 4) ? b2[hh] : 0.f;
      #pragma unroll
      for(int cc = 0; cc < 32; cc++) a += sx2[rr*33 + cc]*sW2t[q*33 + cc];
      if(q < 4) sef[rr*4 + hh] = a;
      else      spr[rr*4 + hh] = a;
    }
    __syncthreads();

    // ================= phase C: attention -> sh =================
    {
      float* scr = sscr + sg*256;
      #pragma unroll
      for(int rep = 0; rep < 4; rep++){
        int j = sg*4 + rep;
        if(j == NA_){
          #pragma unroll
          for(int q = 0; q < 4; q++) sh[j*SHP + q*32 + l] = 0.f;
        } else {
          float prj = spr[j*4 + (l & 3)];
          int hh = l & 3, i0 = l >> 2;
          float pmax = -1e30f;
          #pragma unroll
          for(int k = 0; k < 8; k++){
            int i = i0 + 8*k;
            if(i < NA_){
              float v = eluf(sef[i*4 + hh] + prj);
              scr[i*4 + hh] = v;
              pmax = fmaxf(pmax, v);
            }
          }
          #pragma unroll
          for(int st = 4; st < 32; st <<= 1) pmax = fmaxf(pmax, __shfl_xor(pmax, st, 32));
          float psum = 0.f;
          #pragma unroll
          for(int k = 0; k < 8; k++){
            int i = i0 + 8*k;
            if(i < NA_){
              float e = expf(scr[i*4 + hh] - pmax);
              scr[i*4 + hh] = e;
              psum += e;
            }
          }
          #pragma unroll
          for(int st = 4; st < 32; st <<= 1) psum += __shfl_xor(psum, st, 32);
          if(i0 == 0) scr[252 + hh] = psum;
          float a0=0.f, a1=0.f, a2=0.f, a3=0.f;
          for(int i = 0; i < NA_; i++){
            float4 e4 = *(const float4*)&scr[i*4];
            float xv = sx2[i*33 + l];
            a0 += e4.x*xv; a1 += e4.y*xv; a2 += e4.z*xv; a3 += e4.w*xv;
          }
          sh[j*SHP +      l] = eluf(a0/scr[252]);
          sh[j*SHP + 32 + l] = eluf(a1/scr[253]);
          sh[j*SHP + 64 + l] = eluf(a2/scr[254]);
          sh[j*SHP + 96 + l] = eluf(a3/scr[255]);
        }
      }
    }
    __syncthreads();
  }

  // ---- final Linear(H->D) ----
  if(tid < 128){
    int nn = tid >> 1, d = tid & 1;
    float a = sob[d];
    #pragma unroll 8
    for(int k = 0; k < H_; k++) a += sh[nn*SHP + k]*soW[d*H_ + k];
    pred[((size_t)b*N_ + nn)*D_ + d] = a;
  }
}

extern "C" void kernel_launch(void* const* d_in, const int* in_sizes, int n_in,
                              void* d_out, int out_size, void* d_ws, size_t ws_size,
                              hipStream_t stream){
  const float* inputs = (const float*)d_in[0];
  const float* hidden = (const float*)d_in[1];
  const float* rn1_W1 = (const float*)d_in[4];
  const float* rn1_b1 = (const float*)d_in[5];
  const float* rn1_W2 = (const float*)d_in[6];
  const float* rn1_b2 = (const float*)d_in[7];
  const float* rn2_W1 = (const float*)d_in[8];
  const float* rn2_b1 = (const float*)d_in[9];
  const float* rn2_W2 = (const float*)d_in[10];
  const float* rn2_b2 = (const float*)d_in[11];
  const float* gWih   = (const float*)d_in[12];
  const float* gWhh   = (const float*)d_in[13];
  const float* gbih   = (const float*)d_in[14];
  const float* gbhh   = (const float*)d_in[15];
  const float* oW     = (const float*)d_in[16];
  const float* ob     = (const float*)d_in[17];
  float* ws = (float*)d_ws;

  gat1_fc<<<T_*B_, 256, 0, stream>>>(inputs, rn1_W1, rn1_b1, rn1_W2, rn1_b2,
                                     ws + OFF_X1, ws + OFF_PS1, ws + OFF_PR1);
  att64<<<T_*B_, 512, 0, stream>>>(ws + OFF_X1, ws + OFF_PS1, ws + OFF_PR1,
                                   ws + OFF_XG);
  gi_k<<<T_*B_, 512, 0, stream>>>(ws + OFF_XG, gWih, gbih, gbhh, ws + OFF_GI);
  loop_k<<<B_, 512, 0, stream>>>(ws + OFF_GI, hidden,
                                 gWhh, gbhh,
                                 rn2_W1, rn2_b1, rn2_W2, rn2_b2,
                                 oW, ob, (float*)d_out);
}